// Round 7
// baseline (553.047 us; speedup 1.0000x reference)
//
#include <hip/hip_runtime.h>
#include <hip/hip_bf16.h>
#include <math.h>

// Problem constants
#define BB   2
#define CIN  32
#define COUT 32
#define DM   40
#define PD   42                 // padded spatial dim
#define NPTS (DM*DM)            // 1600
#define NVOL (DM*DM*DM)         // 64000
#define EPSBN 1e-5f
#define NSLOT 64                // stat-accumulator slots (spread atomics)

#define GRID 1000               // <= 1024 co-resident @ 4 blocks/CU (lb 256,4)

typedef short  bf16x8  __attribute__((ext_vector_type(8)));
typedef short  bf16x4  __attribute__((ext_vector_type(4)));
typedef float  floatx4 __attribute__((ext_vector_type(4)));

// Workspace layout (float offsets), all 16B-aligned
#define WS_WFRAG 0              // bf16[55296] = 27648 floats
#define WS_BCOMB 27648          // 64 floats
#define WS_SUM2  27712          // 64 slots * 64 stats = 4096 floats
#define WS_XPAD2 31808          // bf16[2*42^3*32] = 2370816 floats
#define WS_Y     2402624        // bf16[2*32*64000] = 2048000 floats
#define WS_BAR   4450624        // 4 unsigneds: {cnt0, flag0, cnt1, flag1}

#define REPACK_BLOCKS (PD*PD*BB)                  // 3528
#define NW_ELEMS  (2*2*27*64*8)                   // 55296
#define PREP_ELEMS (NW_ELEMS + 64 + NSLOT*64)     // wfrag + bias + zero sums2
#define PREP_UNITS (REPACK_BLOCKS + (PREP_ELEMS + 255) / 256)  // 3761
#define CONV_UNITS (25 * DM * BB)                 // 2000 = 2 * GRID exactly
#define UP_UNITS   (BB * COUT * DM)               // 2560

static __device__ __forceinline__ short f2bf(float f) {
    __hip_bfloat16 h = __float2bfloat16(f);
    return *reinterpret_cast<short*>(&h);
}
static __device__ __forceinline__ float bf2f(short s) {
    union { unsigned u; float f; } cv;
    cv.u = ((unsigned)(unsigned short)s) << 16;
    return cv.f;
}

// Single-use software grid barrier (state zeroed per launch via memsetAsync).
// Release/acquire via flag; threadfence both sides for cross-XCD visibility.
// Spin bailout: a co-residency failure becomes a clean correctness failure,
// never a hang.
static __device__ __forceinline__ void grid_barrier_once(unsigned* cnt,
                                                         unsigned* flag) {
    __syncthreads();
    if (threadIdx.x == 0) {
        __threadfence();                                   // release prior writes
        if (atomicAdd(cnt, 1u) == (unsigned)(GRID - 1)) {  // last arrival
            __hip_atomic_store(flag, 1u, __ATOMIC_RELEASE,
                               __HIP_MEMORY_SCOPE_AGENT);
        } else {
            int spins = 0;
            while (!__hip_atomic_load(flag, __ATOMIC_ACQUIRE,
                                      __HIP_MEMORY_SCOPE_AGENT)) {
                __builtin_amdgcn_s_sleep(4);
                if (++spins > (1 << 22)) break;            // ~0.5s bailout
            }
        }
        __threadfence();                                   // acquire side
    }
    __syncthreads();
}

// ===========================================================================
// Single fused kernel (plain launch): phase1 prep+repack | swbar | phase2
// conv | swbar | phase3 BN+LeakyReLU+upsample. Phase bodies = r5-verified.
// ===========================================================================
__global__ __launch_bounds__(256, 4) void fused_kernel(
        const float* __restrict__ x,
        const float* __restrict__ emb,
        const float* __restrict__ rw,
        const float* __restrict__ rb,
        const float* __restrict__ ek,
        const float* __restrict__ ebias,
        const float* __restrict__ gamma,
        const float* __restrict__ beta,
        float* __restrict__ ws,
        float* __restrict__ out) {
    const int bid = blockIdx.x;
    const int t   = threadIdx.x;
    unsigned* bar = (unsigned*)(ws + WS_BAR);

    __shared__ union {
        short ptile[PD * 32];                             // phase 1 (2688 B)
        struct { float lstat[64]; short ytile[32 * 72]; } c;   // phase 2 (4864 B)
        struct { float partl[4][64]; float ssc[32]; float ssh[32];
                 float fplane[NPTS]; } up;                // phase 3 (7680 B)
    } sm;

    // ---------------- Phase 1: prep + repack (grid-strided units) ----------
    for (int u = bid; u < PREP_UNITS; u += GRID) {
        if (u < REPACK_BLOCKS) {
            int b  = u / (PD * PD);
            int r  = u % (PD * PD);
            int zp = r / PD, yp = r % PD;
            short* row = (short*)(ws + WS_XPAD2) +
                         ((((size_t)b * PD + zp) * PD + yp) * PD) * 32;
            const bool inz = (zp >= 1 && zp <= DM && yp >= 1 && yp <= DM);
            const int i  = t >> 3;          // channel 0..31
            const int xl = t & 7;           // x-lane within 8
            #pragma unroll
            for (int k = 0; k < 6; ++k) {
                int xp = xl + 8 * k;
                if (xp < PD) {
                    float v = 0.0f;
                    if (inz && xp >= 1 && xp <= DM)
                        v = x[(size_t)(b * CIN + i) * NVOL +
                              (zp - 1) * NPTS + (yp - 1) * DM + (xp - 1)];
                    sm.ptile[xp * 32 + i] = f2bf(v);
                }
            }
            __syncthreads();
            const unsigned* ts = (const unsigned*)sm.ptile;
            unsigned* rowu = (unsigned*)row;
            for (int j = t; j < PD * 32 / 2; j += 256) rowu[j] = ts[j];
        } else {
            int idx = (u - REPACK_BLOCKS) * 256 + t;
            short* wfrag = (short*)(ws + WS_WFRAG);
            if (idx < NW_ELEMS) {
                int j    = idx & 7;
                int lane = (idx >> 3) & 63;
                int tap  = (idx >> 9) % 27;
                int nt   = (idx / (27 * 512)) & 1;
                int b    = idx / (2 * 27 * 512);
                int o = nt * 16 + (lane & 15);
                int i = (lane >> 4) * 8 + j;
                float e0 = emb[b];
                float w = 0.0f;
                #pragma unroll
                for (int e = 0; e < 3; ++e) {
                    float r = 1.0f / (1.0f + expf(-(e0 * rw[e] + rb[e])));
                    w += r * ek[((e * COUT + o) * CIN + i) * 27 + tap];
                }
                wfrag[idx] = f2bf(w);
            } else if (idx < NW_ELEMS + 64) {
                int j2 = idx - NW_ELEMS;
                int b = j2 >> 5, o = j2 & 31;
                float e0 = emb[b];
                float bv = 0.0f;
                #pragma unroll
                for (int e = 0; e < 3; ++e) {
                    float r = 1.0f / (1.0f + expf(-(e0 * rw[e] + rb[e])));
                    bv += r * ebias[e * COUT + o];
                }
                ws[WS_BCOMB + j2] = bv;
            } else if (idx < PREP_ELEMS) {
                ws[WS_SUM2 + (idx - NW_ELEMS - 64)] = 0.0f;
            }
        }
        __syncthreads();   // uniform per block: protects sm.ptile reuse
    }

    grid_barrier_once(&bar[0], &bar[1]);

    // ---------------- Phase 2: MFMA conv (2 units/block exactly) -----------
    {
        const __hip_bfloat16* xp2 = (const __hip_bfloat16*)(ws + WS_XPAD2);
        const bf16x8* wfrag = (const bf16x8*)(ws + WS_WFRAG);
        const float* bcomb = ws + WS_BCOMB;
        __hip_bfloat16* y = (__hip_bfloat16*)(ws + WS_Y);
        float* sums2 = ws + WS_SUM2;

        const int lane = t & 63, wv = t >> 6;
        const int mt = wv & 1, nt = wv >> 1;
        const int quad = lane >> 4, l15 = lane & 15;

        for (int u = bid; u < CONV_UNITS; u += GRID) {
            const int mc = u % 25;
            const int z  = (u / 25) % DM;
            const int b  = u / (25 * DM);

            if (t < 64) sm.c.lstat[t] = 0.0f;
            __syncthreads();

            const int pa0 = mc * 64 + mt * 32 + l15;
            const int pa1 = pa0 + 16;
            const int ya0 = pa0 / DM, xa0 = pa0 % DM;
            const int ya1 = pa1 / DM, xa1 = pa1 % DM;
            const char* abase0 = (const char*)xp2 +
                ((((size_t)b * PD + z) * PD + ya0) * PD + xa0) * 64 + quad * 16;
            const char* abase1 = (const char*)xp2 +
                ((((size_t)b * PD + z) * PD + ya1) * PD + xa1) * 64 + quad * 16;
            const bf16x8* wbase = wfrag + ((b * 2 + nt) * 27) * 64 + lane;

            floatx4 acc0 = {0.f, 0.f, 0.f, 0.f};
            floatx4 acc1 = {0.f, 0.f, 0.f, 0.f};
            #pragma unroll
            for (int tap = 0; tap < 27; ++tap) {
                const int dz = tap / 9, dy = (tap / 3) % 3, dx = tap % 3;
                const int aoff = ((dz * PD + dy) * PD + dx) * 64;
                bf16x8 av0 = *(const bf16x8*)(abase0 + aoff);
                bf16x8 av1 = *(const bf16x8*)(abase1 + aoff);
                bf16x8 bv  = wbase[tap * 64];
                acc0 = __builtin_amdgcn_mfma_f32_16x16x32_bf16(av0, bv, acc0, 0, 0, 0);
                acc1 = __builtin_amdgcn_mfma_f32_16x16x32_bf16(av1, bv, acc1, 0, 0, 0);
            }

            const int o = nt * 16 + l15;
            const float bias = bcomb[b * COUT + o];

            float u0 = acc0[0] + bias, u1 = acc0[1] + bias;
            float u2 = acc0[2] + bias, u3 = acc0[3] + bias;
            float w0 = acc1[0] + bias, w1 = acc1[1] + bias;
            float w2 = acc1[2] + bias, w3 = acc1[3] + bias;

            {
                const int s0 = mt * 32 + quad * 4;
                bf16x4 p0 = { f2bf(u0), f2bf(u1), f2bf(u2), f2bf(u3) };
                bf16x4 p1 = { f2bf(w0), f2bf(w1), f2bf(w2), f2bf(w3) };
                *(bf16x4*)&sm.c.ytile[o * 72 + s0]      = p0;
                *(bf16x4*)&sm.c.ytile[o * 72 + s0 + 16] = p1;
            }

            float vs = u0 + u1 + u2 + u3 + w0 + w1 + w2 + w3;
            float vq = u0*u0 + u1*u1 + u2*u2 + u3*u3
                     + w0*w0 + w1*w1 + w2*w2 + w3*w3;
            vs += __shfl_xor(vs, 16); vq += __shfl_xor(vq, 16);
            vs += __shfl_xor(vs, 32); vq += __shfl_xor(vq, 32);
            if (lane < 16) {
                atomicAdd(&sm.c.lstat[o],      vs);
                atomicAdd(&sm.c.lstat[32 + o], vq);
            }
            __syncthreads();   // covers ytile writes + lstat atomics

            {
                const int o2 = t >> 3, c = t & 7;
                bf16x8 v = *(const bf16x8*)&sm.c.ytile[o2 * 72 + c * 8];
                __hip_bfloat16* dst = y +
                    ((size_t)(b * COUT + o2) * DM + z) * NPTS + mc * 64 + c * 8;
                *(bf16x8*)dst = v;
            }
            if (t < 64) {
                int slot = ((b * DM + z) * 25 + mc) & (NSLOT - 1);
                atomicAdd(&sums2[slot * 64 + t], sm.c.lstat[t]);
            }
            __syncthreads();   // isolate lstat/ytile across units
        }
    }

    grid_barrier_once(&bar[2], &bar[3]);

    // ---------------- Phase 3: BN + LeakyReLU + upsample -------------------
    {
        const __hip_bfloat16* yin = (const __hip_bfloat16*)(ws + WS_Y);
        const float* sums2 = ws + WS_SUM2;

        // Phase A once per block: slots -> per-channel scale/shift
        {
            int sg = t >> 6, st = t & 63;
            float p = 0.0f;
            #pragma unroll
            for (int s = 0; s < 16; ++s) p += sums2[(sg * 16 + s) * 64 + st];
            sm.up.partl[sg][st] = p;
        }
        __syncthreads();
        if (t < 64) {
            sm.up.partl[0][t] += sm.up.partl[1][t] + sm.up.partl[2][t]
                               + sm.up.partl[3][t];
        }
        __syncthreads();
        if (t < 32) {
            const float invN = 1.0f / (float)(BB * NVOL);
            float mean  = sm.up.partl[0][t] * invN;
            float var   = sm.up.partl[0][32 + t] * invN - mean * mean;
            float scale = gamma[t] * rsqrtf(var + EPSBN);
            sm.up.ssc[t] = scale;
            sm.up.ssh[t] = beta[t] - mean * scale;
        }
        __syncthreads();

        for (int u = bid; u < UP_UNITS; u += GRID) {
            const int cc = u / DM;          // b*COUT + c
            const int z  = u % DM;
            const int c  = cc & 31;
            const float sc = sm.up.ssc[c], sh = sm.up.ssh[c];

            if (t < NPTS / 8) {
                bf16x8 rv = *(const bf16x8*)(yin +
                    ((size_t)cc * DM + z) * NPTS + t * 8);
                #pragma unroll
                for (int j = 0; j < 8; ++j) {
                    float v = bf2f(rv[j]) * sc + sh;
                    sm.up.fplane[t * 8 + j] = (v >= 0.0f) ? v : 0.1f * v;
                }
            }
            __syncthreads();

            float* outp = out + ((size_t)cc * 80 + 2 * z) * 6400;
            for (int cch = t; cch < 2 * 1600; cch += 256) {
                int plane = cch / 1600;
                int cp    = cch - plane * 1600;
                int yy2   = cp / 20;
                int sx0   = (cp % 20) * 2;
                const float* srow = sm.up.fplane + (yy2 >> 1) * DM;
                float v0 = srow[sx0], v1 = srow[sx0 + 1];
                floatx4 q = {v0, v0, v1, v1};
                *(floatx4*)(outp + (size_t)plane * 6400 + cp * 4) = q;
            }
            __syncthreads();   // fplane reuse across units
        }
    }
}

// ---------------------------------------------------------------------------
extern "C" void kernel_launch(void* const* d_in, const int* in_sizes, int n_in,
                              void* d_out, int out_size, void* d_ws, size_t ws_size,
                              hipStream_t stream) {
    const float* x     = (const float*)d_in[0];
    const float* emb   = (const float*)d_in[1];
    const float* rw    = (const float*)d_in[2];
    const float* rb    = (const float*)d_in[3];
    const float* ek    = (const float*)d_in[4];
    const float* ebias = (const float*)d_in[5];
    const float* gamma = (const float*)d_in[6];
    const float* beta  = (const float*)d_in[7];
    float* ws  = (float*)d_ws;
    float* out = (float*)d_out;

    // zero the software-barrier state (ws is re-poisoned between iterations)
    hipMemsetAsync(ws + WS_BAR, 0, 4 * sizeof(unsigned), stream);

    fused_kernel<<<GRID, 256, 0, stream>>>(
        x, emb, rw, rb, ek, ebias, gamma, beta, ws, out);
}

// Round 8
// 448.554 us; speedup vs baseline: 1.2330x; 1.2330x over previous
//
#include <hip/hip_runtime.h>
#include <hip/hip_bf16.h>
#include <math.h>

// Problem constants
#define BB   2
#define CIN  32
#define COUT 32
#define DM   40
#define PD   42                 // padded spatial dim
#define NPTS (DM*DM)            // 1600
#define NVOL (DM*DM*DM)         // 64000
#define EPSBN 1e-5f
#define NSLOT 64                // stat-accumulator slots (spread atomics)

#define GRID 1000               // <= 1024 co-resident @ 4 blocks/CU (lb 256,4)

typedef short  bf16x8  __attribute__((ext_vector_type(8)));
typedef short  bf16x4  __attribute__((ext_vector_type(4)));
typedef float  floatx4 __attribute__((ext_vector_type(4)));

// Workspace layout (float offsets), all 16B-aligned
#define WS_WFRAG 0              // bf16[55296] = 27648 floats
#define WS_BCOMB 27648          // 64 floats
#define WS_SUM2  27712          // 64 slots * 64 stats = 4096 floats
#define WS_XPAD2 31808          // bf16[2*42^3*32] = 2370816 floats
#define WS_Y     2402624        // bf16[2*32*64000] = 2048000 floats
#define WS_BAR   4450624        // 2 barriers x 320 uints (10 x 128B lines each)

#define REPACK_BLOCKS (PD*PD*BB)                  // 3528
#define NW_ELEMS  (2*2*27*64*8)                   // 55296
#define PREP_ELEMS (NW_ELEMS + 64 + NSLOT*64)     // wfrag + bias + zero sums2
#define PREP_UNITS (REPACK_BLOCKS + (PREP_ELEMS + 255) / 256)  // 3761
#define CONV_UNITS (25 * DM * BB)                 // 2000 = 2 * GRID exactly
#define UP_UNITS   (BB * COUT * DM)               // 2560

static __device__ __forceinline__ short f2bf(float f) {
    __hip_bfloat16 h = __float2bfloat16(f);
    return *reinterpret_cast<short*>(&h);
}
static __device__ __forceinline__ float bf2f(short s) {
    union { unsigned u; float f; } cv;
    cv.u = ((unsigned)(unsigned short)s) << 16;
    return cv.f;
}

// ---------------------------------------------------------------------------
// Software grid barrier v2 (r7's v1 spent ~400us: cnt+flag shared a cache
// line, so 999 spinners at s_sleep(4) starved the arrival RMW stream).
// v2: (a) every counter/flag on its own 128B line; (b) hierarchical arrival
// -- 8 sub-counters (1000 = 8*125 exactly) in parallel lines, then 8 adds on
// a root line; (c) s_sleep(32) polling (~0.85us granularity) on a read-only
// line. Single-use per launch; state zeroed by memsetAsync in kernel_launch.
// Layout per barrier (uint offsets): sub[g]=g*32 (g=0..7), root=256, flag=288.
// ---------------------------------------------------------------------------
static __device__ __forceinline__ void grid_barrier(unsigned* base) {
    __syncthreads();
    if (threadIdx.x == 0) {
        __threadfence();                                   // release prior writes
        unsigned g = blockIdx.x & 7;
        unsigned* flag = base + 288;
        if (atomicAdd(base + g * 32, 1u) == 124u) {        // last in group of 125
            if (atomicAdd(base + 256, 1u) == 7u) {         // last group of 8
                __hip_atomic_store(flag, 1u, __ATOMIC_RELEASE,
                                   __HIP_MEMORY_SCOPE_AGENT);
            }
        }
        int spins = 0;
        while (!__hip_atomic_load(flag, __ATOMIC_ACQUIRE,
                                  __HIP_MEMORY_SCOPE_AGENT)) {
            __builtin_amdgcn_s_sleep(32);                  // ~2048 clk per poll
            if (++spins > (1 << 17)) break;                // ~110ms bailout
        }
        __threadfence();                                   // acquire side
    }
    __syncthreads();
}

// ===========================================================================
// Single fused kernel (plain launch): phase1 prep+repack | swbar | phase2
// conv | swbar | phase3 BN+LeakyReLU+upsample. Phase bodies = r7-verified.
// ===========================================================================
__global__ __launch_bounds__(256, 4) void fused_kernel(
        const float* __restrict__ x,
        const float* __restrict__ emb,
        const float* __restrict__ rw,
        const float* __restrict__ rb,
        const float* __restrict__ ek,
        const float* __restrict__ ebias,
        const float* __restrict__ gamma,
        const float* __restrict__ beta,
        float* __restrict__ ws,
        float* __restrict__ out) {
    const int bid = blockIdx.x;
    const int t   = threadIdx.x;
    unsigned* bar = (unsigned*)(ws + WS_BAR);

    __shared__ union {
        short ptile[PD * 32];                             // phase 1 (2688 B)
        struct { float lstat[64]; short ytile[32 * 72]; } c;   // phase 2 (4864 B)
        struct { float partl[4][64]; float ssc[32]; float ssh[32];
                 float fplane[NPTS]; } up;                // phase 3 (7680 B)
    } sm;

    // ---------------- Phase 1: prep + repack (grid-strided units) ----------
    for (int u = bid; u < PREP_UNITS; u += GRID) {
        if (u < REPACK_BLOCKS) {
            int b  = u / (PD * PD);
            int r  = u % (PD * PD);
            int zp = r / PD, yp = r % PD;
            short* row = (short*)(ws + WS_XPAD2) +
                         ((((size_t)b * PD + zp) * PD + yp) * PD) * 32;
            const bool inz = (zp >= 1 && zp <= DM && yp >= 1 && yp <= DM);
            const int i  = t >> 3;          // channel 0..31
            const int xl = t & 7;           // x-lane within 8
            #pragma unroll
            for (int k = 0; k < 6; ++k) {
                int xp = xl + 8 * k;
                if (xp < PD) {
                    float v = 0.0f;
                    if (inz && xp >= 1 && xp <= DM)
                        v = x[(size_t)(b * CIN + i) * NVOL +
                              (zp - 1) * NPTS + (yp - 1) * DM + (xp - 1)];
                    sm.ptile[xp * 32 + i] = f2bf(v);
                }
            }
            __syncthreads();
            const unsigned* ts = (const unsigned*)sm.ptile;
            unsigned* rowu = (unsigned*)row;
            for (int j = t; j < PD * 32 / 2; j += 256) rowu[j] = ts[j];
        } else {
            int idx = (u - REPACK_BLOCKS) * 256 + t;
            short* wfrag = (short*)(ws + WS_WFRAG);
            if (idx < NW_ELEMS) {
                int j    = idx & 7;
                int lane = (idx >> 3) & 63;
                int tap  = (idx >> 9) % 27;
                int nt   = (idx / (27 * 512)) & 1;
                int b    = idx / (2 * 27 * 512);
                int o = nt * 16 + (lane & 15);
                int i = (lane >> 4) * 8 + j;
                float e0 = emb[b];
                float w = 0.0f;
                #pragma unroll
                for (int e = 0; e < 3; ++e) {
                    float r = 1.0f / (1.0f + expf(-(e0 * rw[e] + rb[e])));
                    w += r * ek[((e * COUT + o) * CIN + i) * 27 + tap];
                }
                wfrag[idx] = f2bf(w);
            } else if (idx < NW_ELEMS + 64) {
                int j2 = idx - NW_ELEMS;
                int b = j2 >> 5, o = j2 & 31;
                float e0 = emb[b];
                float bv = 0.0f;
                #pragma unroll
                for (int e = 0; e < 3; ++e) {
                    float r = 1.0f / (1.0f + expf(-(e0 * rw[e] + rb[e])));
                    bv += r * ebias[e * COUT + o];
                }
                ws[WS_BCOMB + j2] = bv;
            } else if (idx < PREP_ELEMS) {
                ws[WS_SUM2 + (idx - NW_ELEMS - 64)] = 0.0f;
            }
        }
        __syncthreads();   // uniform per block: protects sm.ptile reuse
    }

    grid_barrier(bar);

    // ---------------- Phase 2: MFMA conv (2 units/block exactly) -----------
    {
        const __hip_bfloat16* xp2 = (const __hip_bfloat16*)(ws + WS_XPAD2);
        const bf16x8* wfrag = (const bf16x8*)(ws + WS_WFRAG);
        const float* bcomb = ws + WS_BCOMB;
        __hip_bfloat16* y = (__hip_bfloat16*)(ws + WS_Y);
        float* sums2 = ws + WS_SUM2;

        const int lane = t & 63, wv = t >> 6;
        const int mt = wv & 1, nt = wv >> 1;
        const int quad = lane >> 4, l15 = lane & 15;

        for (int u = bid; u < CONV_UNITS; u += GRID) {
            const int mc = u % 25;
            const int z  = (u / 25) % DM;
            const int b  = u / (25 * DM);

            if (t < 64) sm.c.lstat[t] = 0.0f;
            __syncthreads();

            const int pa0 = mc * 64 + mt * 32 + l15;
            const int pa1 = pa0 + 16;
            const int ya0 = pa0 / DM, xa0 = pa0 % DM;
            const int ya1 = pa1 / DM, xa1 = pa1 % DM;
            const char* abase0 = (const char*)xp2 +
                ((((size_t)b * PD + z) * PD + ya0) * PD + xa0) * 64 + quad * 16;
            const char* abase1 = (const char*)xp2 +
                ((((size_t)b * PD + z) * PD + ya1) * PD + xa1) * 64 + quad * 16;
            const bf16x8* wbase = wfrag + ((b * 2 + nt) * 27) * 64 + lane;

            floatx4 acc0 = {0.f, 0.f, 0.f, 0.f};
            floatx4 acc1 = {0.f, 0.f, 0.f, 0.f};
            #pragma unroll
            for (int tap = 0; tap < 27; ++tap) {
                const int dz = tap / 9, dy = (tap / 3) % 3, dx = tap % 3;
                const int aoff = ((dz * PD + dy) * PD + dx) * 64;
                bf16x8 av0 = *(const bf16x8*)(abase0 + aoff);
                bf16x8 av1 = *(const bf16x8*)(abase1 + aoff);
                bf16x8 bv  = wbase[tap * 64];
                acc0 = __builtin_amdgcn_mfma_f32_16x16x32_bf16(av0, bv, acc0, 0, 0, 0);
                acc1 = __builtin_amdgcn_mfma_f32_16x16x32_bf16(av1, bv, acc1, 0, 0, 0);
            }

            const int o = nt * 16 + l15;
            const float bias = bcomb[b * COUT + o];

            float u0 = acc0[0] + bias, u1 = acc0[1] + bias;
            float u2 = acc0[2] + bias, u3 = acc0[3] + bias;
            float w0 = acc1[0] + bias, w1 = acc1[1] + bias;
            float w2 = acc1[2] + bias, w3 = acc1[3] + bias;

            {
                const int s0 = mt * 32 + quad * 4;
                bf16x4 p0 = { f2bf(u0), f2bf(u1), f2bf(u2), f2bf(u3) };
                bf16x4 p1 = { f2bf(w0), f2bf(w1), f2bf(w2), f2bf(w3) };
                *(bf16x4*)&sm.c.ytile[o * 72 + s0]      = p0;
                *(bf16x4*)&sm.c.ytile[o * 72 + s0 + 16] = p1;
            }

            float vs = u0 + u1 + u2 + u3 + w0 + w1 + w2 + w3;
            float vq = u0*u0 + u1*u1 + u2*u2 + u3*u3
                     + w0*w0 + w1*w1 + w2*w2 + w3*w3;
            vs += __shfl_xor(vs, 16); vq += __shfl_xor(vq, 16);
            vs += __shfl_xor(vs, 32); vq += __shfl_xor(vq, 32);
            if (lane < 16) {
                atomicAdd(&sm.c.lstat[o],      vs);
                atomicAdd(&sm.c.lstat[32 + o], vq);
            }
            __syncthreads();   // covers ytile writes + lstat atomics

            {
                const int o2 = t >> 3, c = t & 7;
                bf16x8 v = *(const bf16x8*)&sm.c.ytile[o2 * 72 + c * 8];
                __hip_bfloat16* dst = y +
                    ((size_t)(b * COUT + o2) * DM + z) * NPTS + mc * 64 + c * 8;
                *(bf16x8*)dst = v;
            }
            if (t < 64) {
                int slot = ((b * DM + z) * 25 + mc) & (NSLOT - 1);
                atomicAdd(&sums2[slot * 64 + t], sm.c.lstat[t]);
            }
            __syncthreads();   // isolate lstat/ytile across units
        }
    }

    grid_barrier(bar + 320);

    // ---------------- Phase 3: BN + LeakyReLU + upsample -------------------
    {
        const __hip_bfloat16* yin = (const __hip_bfloat16*)(ws + WS_Y);
        const float* sums2 = ws + WS_SUM2;

        // Phase A once per block: slots -> per-channel scale/shift
        {
            int sg = t >> 6, st = t & 63;
            float p = 0.0f;
            #pragma unroll
            for (int s = 0; s < 16; ++s) p += sums2[(sg * 16 + s) * 64 + st];
            sm.up.partl[sg][st] = p;
        }
        __syncthreads();
        if (t < 64) {
            sm.up.partl[0][t] += sm.up.partl[1][t] + sm.up.partl[2][t]
                               + sm.up.partl[3][t];
        }
        __syncthreads();
        if (t < 32) {
            const float invN = 1.0f / (float)(BB * NVOL);
            float mean  = sm.up.partl[0][t] * invN;
            float var   = sm.up.partl[0][32 + t] * invN - mean * mean;
            float scale = gamma[t] * rsqrtf(var + EPSBN);
            sm.up.ssc[t] = scale;
            sm.up.ssh[t] = beta[t] - mean * scale;
        }
        __syncthreads();

        for (int u = bid; u < UP_UNITS; u += GRID) {
            const int cc = u / DM;          // b*COUT + c
            const int z  = u % DM;
            const int c  = cc & 31;
            const float sc = sm.up.ssc[c], sh = sm.up.ssh[c];

            if (t < NPTS / 8) {
                bf16x8 rv = *(const bf16x8*)(yin +
                    ((size_t)cc * DM + z) * NPTS + t * 8);
                #pragma unroll
                for (int j = 0; j < 8; ++j) {
                    float v = bf2f(rv[j]) * sc + sh;
                    sm.up.fplane[t * 8 + j] = (v >= 0.0f) ? v : 0.1f * v;
                }
            }
            __syncthreads();

            float* outp = out + ((size_t)cc * 80 + 2 * z) * 6400;
            for (int cch = t; cch < 2 * 1600; cch += 256) {
                int plane = cch / 1600;
                int cp    = cch - plane * 1600;
                int yy2   = cp / 20;
                int sx0   = (cp % 20) * 2;
                const float* srow = sm.up.fplane + (yy2 >> 1) * DM;
                float v0 = srow[sx0], v1 = srow[sx0 + 1];
                floatx4 q = {v0, v0, v1, v1};
                *(floatx4*)(outp + (size_t)plane * 6400 + cp * 4) = q;
            }
            __syncthreads();   // fplane reuse across units
        }
    }
}

// ---------------------------------------------------------------------------
extern "C" void kernel_launch(void* const* d_in, const int* in_sizes, int n_in,
                              void* d_out, int out_size, void* d_ws, size_t ws_size,
                              hipStream_t stream) {
    const float* x     = (const float*)d_in[0];
    const float* emb   = (const float*)d_in[1];
    const float* rw    = (const float*)d_in[2];
    const float* rb    = (const float*)d_in[3];
    const float* ek    = (const float*)d_in[4];
    const float* ebias = (const float*)d_in[5];
    const float* gamma = (const float*)d_in[6];
    const float* beta  = (const float*)d_in[7];
    float* ws  = (float*)d_ws;
    float* out = (float*)d_out;

    // zero both barriers' state (2 x 320 uints); ws is re-poisoned per iter
    hipMemsetAsync(ws + WS_BAR, 0, 2 * 320 * sizeof(unsigned), stream);

    fused_kernel<<<GRID, 256, 0, stream>>>(
        x, emb, rw, rb, ek, ebias, gamma, beta, ws, out);
}

// Round 9
// 198.251 us; speedup vs baseline: 2.7896x; 2.2626x over previous
//
#include <hip/hip_runtime.h>
#include <hip/hip_bf16.h>
#include <math.h>

// Problem constants
#define BB   2
#define CIN  32
#define COUT 32
#define DM   40
#define PD   42                 // padded spatial dim
#define NPTS (DM*DM)            // 1600
#define NVOL (DM*DM*DM)         // 64000
#define EPSBN 1e-5f
#define NSLOT 64                // stat-accumulator slots (spread atomics)

typedef short  bf16x8  __attribute__((ext_vector_type(8)));
typedef short  bf16x4  __attribute__((ext_vector_type(4)));
typedef float  floatx4 __attribute__((ext_vector_type(4)));

// Workspace layout (float offsets), all 16B-aligned
#define WS_WFRAG 0              // bf16[55296] = 27648 floats
#define WS_BCOMB 27648          // 64 floats
#define WS_SUM2  27712          // 64 slots * 64 stats = 4096 floats
#define WS_XPAD2 31808          // bf16[2*42^3*32] = 2370816 floats
#define WS_Y     2402624        // bf16[2*32*64000] = 2048000 floats

#define REPACK_BLOCKS (PD*PD*BB)                  // 3528
#define NW_ELEMS  (2*2*27*64*8)                   // 55296
#define PREP_ELEMS (NW_ELEMS + 64 + NSLOT*64)     // wfrag + bias + zero sums2
#define PREP_BLOCKS ((PREP_ELEMS + 255) / 256)    // 233

static __device__ __forceinline__ short f2bf(float f) {
    __hip_bfloat16 h = __float2bfloat16(f);
    return *reinterpret_cast<short*>(&h);
}
static __device__ __forceinline__ float bf2f(short s) {
    union { unsigned u; float f; } cv;
    cv.u = ((unsigned)(unsigned short)s) << 16;
    return cv.f;
}

// ---------------------------------------------------------------------------
// Kernel 1: fused prep (routing + B-fragment weights + bias + zero stat slots)
//           and channels-last zero-padded bf16 repack of x. (r5-verified)
// ---------------------------------------------------------------------------
__global__ void prep_repack_kernel(const float* __restrict__ x,
                                   const float* __restrict__ emb,
                                   const float* __restrict__ rw,
                                   const float* __restrict__ rb,
                                   const float* __restrict__ ek,
                                   const float* __restrict__ ebias,
                                   float* __restrict__ ws) {
    __shared__ __hip_bfloat16 tile[PD * 32];   // 2688 B, layout [xp][i]
    const int bid = blockIdx.x;
    const int t = threadIdx.x;
    if (bid < REPACK_BLOCKS) {
        // ---- repack role ----
        int b  = bid / (PD * PD);
        int r  = bid % (PD * PD);
        int zp = r / PD, yp = r % PD;
        __hip_bfloat16* row = (__hip_bfloat16*)(ws + WS_XPAD2) +
                              ((((size_t)b * PD + zp) * PD + yp) * PD) * 32;
        const bool inz = (zp >= 1 && zp <= DM && yp >= 1 && yp <= DM);
        const int i  = t >> 3;          // channel 0..31
        const int xl = t & 7;           // x-lane within 8
        #pragma unroll
        for (int k = 0; k < 6; ++k) {
            int xp = xl + 8 * k;
            if (xp < PD) {
                float v = 0.0f;
                if (inz && xp >= 1 && xp <= DM)
                    v = x[(size_t)(b * CIN + i) * NVOL +
                          (zp - 1) * NPTS + (yp - 1) * DM + (xp - 1)];
                tile[xp * 32 + i] = __float2bfloat16(v);
            }
        }
        __syncthreads();
        // flat coalesced copy: 672 dwords
        const unsigned* ts = (const unsigned*)tile;
        unsigned* rowu = (unsigned*)row;
        for (int j = t; j < PD * 32 / 2; j += 256) rowu[j] = ts[j];
        return;
    }
    // ---- prep role ----
    int idx = (bid - REPACK_BLOCKS) * 256 + t;
    __hip_bfloat16* wfrag = (__hip_bfloat16*)(ws + WS_WFRAG);
    if (idx < NW_ELEMS) {
        int j    = idx & 7;
        int lane = (idx >> 3) & 63;
        int tap  = (idx >> 9) % 27;
        int nt   = (idx / (27 * 512)) & 1;
        int b    = idx / (2 * 27 * 512);
        int o = nt * 16 + (lane & 15);
        int i = (lane >> 4) * 8 + j;
        float e0 = emb[b];
        float w = 0.0f;
        #pragma unroll
        for (int e = 0; e < 3; ++e) {
            float r = 1.0f / (1.0f + expf(-(e0 * rw[e] + rb[e])));
            w += r * ek[((e * COUT + o) * CIN + i) * 27 + tap];
        }
        wfrag[idx] = __float2bfloat16(w);
    } else if (idx < NW_ELEMS + 64) {
        int j2 = idx - NW_ELEMS;
        int b = j2 >> 5, o = j2 & 31;
        float e0 = emb[b];
        float bv = 0.0f;
        #pragma unroll
        for (int e = 0; e < 3; ++e) {
            float r = 1.0f / (1.0f + expf(-(e0 * rw[e] + rb[e])));
            bv += r * ebias[e * COUT + o];
        }
        ws[WS_BCOMB + j2] = bv;
    } else if (idx < PREP_ELEMS) {
        ws[WS_SUM2 + (idx - NW_ELEMS - 64)] = 0.0f;   // zero sums2[64][64]
    }
}

// ---------------------------------------------------------------------------
// Kernel 2: implicit-GEMM conv via MFMA bf16, LDS-staged coalesced y store.
// NEW (r8): XCD-affine z-partition + 8 blocks/CU.
//   Flat grid 2000 = 8 XCDs x 250. Decode: g=bid&7 (XCD via round-robin
//   dispatch), each XCD owns z in [5g, 5g+5) for both batches -> its A-window
//   (7 z-planes x 2b ~ 1.6MB) L2-resident; the 9x neighbor reuse (z+-1,y+-1)
//   becomes L2 hits instead of cross-XCD misses (r3: 50MB L2-miss fetch,
//   latency-bound at MfmaUtil 5%). launch_bounds(256,8): 48 VGPR build ->
//   all 2000 blocks co-resident, 2x waves to hide remaining misses.
// ---------------------------------------------------------------------------
__global__ __launch_bounds__(256, 8) void conv_mfma_kernel(
        const __hip_bfloat16* __restrict__ xp2,
        const bf16x8* __restrict__ wfrag,
        const float* __restrict__ bcomb,
        __hip_bfloat16* __restrict__ y,
        float* __restrict__ sums2) {
    const int g   = blockIdx.x & 7;          // XCD id (round-robin assumption)
    const int s   = blockIdx.x >> 3;         // 0..249 slot within XCD
    const int b   = s / 125;
    const int rem = s % 125;
    const int z   = g * 5 + rem / 25;        // XCD g owns z in [5g, 5g+5)
    const int mc  = rem % 25;

    const int tid = threadIdx.x, lane = tid & 63, wv = tid >> 6;
    const int mt = wv & 1, nt = wv >> 1;
    const int quad = lane >> 4, l15 = lane & 15;

    __shared__ float lstat[64];
    __shared__ short ytile[32 * 72];    // [o][s], s-pitch 72 (144B, 16B-aligned)

    if (tid < 64) lstat[tid] = 0.0f;
    __syncthreads();

    const int pa0 = mc * 64 + mt * 32 + l15;
    const int pa1 = pa0 + 16;
    const int ya0 = pa0 / DM, xa0 = pa0 % DM;
    const int ya1 = pa1 / DM, xa1 = pa1 % DM;
    const char* abase0 = (const char*)xp2 +
        ((((size_t)b * PD + z) * PD + ya0) * PD + xa0) * 64 + quad * 16;
    const char* abase1 = (const char*)xp2 +
        ((((size_t)b * PD + z) * PD + ya1) * PD + xa1) * 64 + quad * 16;
    const bf16x8* wbase = wfrag + ((b * 2 + nt) * 27) * 64 + lane;

    floatx4 acc0 = {0.f, 0.f, 0.f, 0.f};
    floatx4 acc1 = {0.f, 0.f, 0.f, 0.f};
    #pragma unroll
    for (int t = 0; t < 27; ++t) {
        const int dz = t / 9, dy = (t / 3) % 3, dx = t % 3;
        const int aoff = ((dz * PD + dy) * PD + dx) * 64;
        bf16x8 av0 = *(const bf16x8*)(abase0 + aoff);
        bf16x8 av1 = *(const bf16x8*)(abase1 + aoff);
        bf16x8 bv  = wbase[t * 64];
        acc0 = __builtin_amdgcn_mfma_f32_16x16x32_bf16(av0, bv, acc0, 0, 0, 0);
        acc1 = __builtin_amdgcn_mfma_f32_16x16x32_bf16(av1, bv, acc1, 0, 0, 0);
    }

    const int o = nt * 16 + l15;
    const float bias = bcomb[b * COUT + o];

    float u0 = acc0[0] + bias, u1 = acc0[1] + bias;
    float u2 = acc0[2] + bias, u3 = acc0[3] + bias;
    float w0 = acc1[0] + bias, w1 = acc1[1] + bias;
    float w2 = acc1[2] + bias, w3 = acc1[3] + bias;

    {
        const int s0 = mt * 32 + quad * 4;
        bf16x4 p0 = { f2bf(u0), f2bf(u1), f2bf(u2), f2bf(u3) };
        bf16x4 p1 = { f2bf(w0), f2bf(w1), f2bf(w2), f2bf(w3) };
        *(bf16x4*)&ytile[o * 72 + s0]      = p0;
        *(bf16x4*)&ytile[o * 72 + s0 + 16] = p1;
    }

    float vs = u0 + u1 + u2 + u3 + w0 + w1 + w2 + w3;
    float vq = u0*u0 + u1*u1 + u2*u2 + u3*u3 + w0*w0 + w1*w1 + w2*w2 + w3*w3;
    vs += __shfl_xor(vs, 16); vq += __shfl_xor(vq, 16);
    vs += __shfl_xor(vs, 32); vq += __shfl_xor(vq, 32);
    if (lane < 16) {
        atomicAdd(&lstat[o],      vs);
        atomicAdd(&lstat[32 + o], vq);
    }
    __syncthreads();   // covers ytile writes + lstat atomics

    {
        const int o2 = tid >> 3, c = tid & 7;
        bf16x8 v = *(const bf16x8*)&ytile[o2 * 72 + c * 8];
        __hip_bfloat16* dst = y + ((size_t)(b * COUT + o2) * DM + z) * NPTS
                            + mc * 64 + c * 8;
        *(bf16x8*)dst = v;
    }
    if (tid < 64) {
        int slot = ((b * DM + z) * 25 + mc) & (NSLOT - 1);
        atomicAdd(&sums2[slot * 64 + tid], lstat[tid]);
    }
}

// ---------------------------------------------------------------------------
// Kernel 3: plane-based BN + LeakyReLU + upsample. (r5-verified)
// ---------------------------------------------------------------------------
__global__ __launch_bounds__(256) void upsample_kernel(
        const __hip_bfloat16* __restrict__ yin,
        const float* __restrict__ sums2,
        const float* __restrict__ gamma,
        const float* __restrict__ beta,
        float* __restrict__ out) {
    __shared__ float partl[4][64];
    __shared__ float ssc[32], ssh[32];
    __shared__ float fplane[NPTS];          // normalized src plane (6.4 KB)
    const int tid = threadIdx.x;
    const int cc  = blockIdx.x / DM;        // b*COUT + c
    const int z   = blockIdx.x % DM;
    const int c   = cc & 31;

    // Phase A: reduce 64 stat slots -> per-channel scale/shift
    {
        int sg = tid >> 6, st = tid & 63;
        float p = 0.0f;
        #pragma unroll
        for (int s = 0; s < 16; ++s) p += sums2[(sg * 16 + s) * 64 + st];
        partl[sg][st] = p;
    }
    __syncthreads();
    if (tid < 64) {
        partl[0][tid] += partl[1][tid] + partl[2][tid] + partl[3][tid];
    }
    __syncthreads();
    if (tid < 32) {
        const float invN = 1.0f / (float)(BB * NVOL);
        float mean  = partl[0][tid] * invN;
        float var   = partl[0][32 + tid] * invN - mean * mean;
        float scale = gamma[tid] * rsqrtf(var + EPSBN);
        ssc[tid] = scale;
        ssh[tid] = beta[tid] - mean * scale;
    }
    __syncthreads();

    // Phase B: normalize src plane into LDS (200 threads x bf16x8 = 16B loads)
    const float sc = ssc[c], sh = ssh[c];
    if (tid < NPTS / 8) {
        bf16x8 rv = *(const bf16x8*)(yin + ((size_t)cc * DM + z) * NPTS + tid * 8);
        #pragma unroll
        for (int j = 0; j < 8; ++j) {
            float v = bf2f(rv[j]) * sc + sh;
            fplane[tid * 8 + j] = (v >= 0.0f) ? v : 0.1f * v;
        }
    }
    __syncthreads();

    // Phase C: write dst planes 2z and 2z+1 as lane-consecutive floatx4 chunks
    float* outp = out + ((size_t)cc * 80 + 2 * z) * 6400;
    #pragma unroll 2
    for (int cch = tid; cch < 2 * 1600; cch += 256) {
        int plane = cch / 1600;
        int cp    = cch - plane * 1600;
        int yy2   = cp / 20;
        int sx0   = (cp % 20) * 2;
        const float* srow = fplane + (yy2 >> 1) * DM;
        float v0 = srow[sx0], v1 = srow[sx0 + 1];
        floatx4 q = {v0, v0, v1, v1};
        *(floatx4*)(outp + (size_t)plane * 6400 + cp * 4) = q;
    }
}

// ---------------------------------------------------------------------------
extern "C" void kernel_launch(void* const* d_in, const int* in_sizes, int n_in,
                              void* d_out, int out_size, void* d_ws, size_t ws_size,
                              hipStream_t stream) {
    const float* x     = (const float*)d_in[0];
    const float* emb   = (const float*)d_in[1];
    const float* rw    = (const float*)d_in[2];
    const float* rb    = (const float*)d_in[3];
    const float* ek    = (const float*)d_in[4];
    const float* ebias = (const float*)d_in[5];
    const float* gamma = (const float*)d_in[6];
    const float* beta  = (const float*)d_in[7];
    float* ws  = (float*)d_ws;
    float* out = (float*)d_out;

    // 1: prep + repack (+ zero stat slots)
    prep_repack_kernel<<<REPACK_BLOCKS + PREP_BLOCKS, 256, 0, stream>>>(
        x, emb, rw, rb, ek, ebias, ws);

    // 2: MFMA conv, XCD-affine flat grid (2000 = 8 x 250)
    conv_mfma_kernel<<<2000, 256, 0, stream>>>(
        (const __hip_bfloat16*)(ws + WS_XPAD2), (const bf16x8*)(ws + WS_WFRAG),
        ws + WS_BCOMB, (__hip_bfloat16*)(ws + WS_Y), ws + WS_SUM2);

    // 3: plane-based BN + LeakyReLU + upsample
    upsample_kernel<<<BB * COUT * DM, 256, 0, stream>>>(
        (const __hip_bfloat16*)(ws + WS_Y), ws + WS_SUM2, gamma, beta, out);
}

// Round 10
// 179.152 us; speedup vs baseline: 3.0870x; 1.1066x over previous
//
#include <hip/hip_runtime.h>
#include <hip/hip_bf16.h>
#include <math.h>

// Problem constants
#define BB   2
#define CIN  32
#define COUT 32
#define DM   40
#define PD   42                 // padded spatial dim
#define NPTS (DM*DM)            // 1600
#define NVOL (DM*DM*DM)         // 64000
#define EPSBN 1e-5f
#define NSLOT 64                // stat-accumulator slots (spread atomics)

typedef short  bf16x8  __attribute__((ext_vector_type(8)));
typedef short  bf16x4  __attribute__((ext_vector_type(4)));
typedef float  floatx4 __attribute__((ext_vector_type(4)));

// Workspace layout (float offsets), all 16B-aligned
#define WS_WFRAG 0              // bf16[55296] = 27648 floats
#define WS_BCOMB 27648          // 64 floats
#define WS_SUM2  27712          // 64 slots * 64 stats = 4096 floats
#define WS_XPAD2 31808          // bf16[2*42^3*32] = 2370816 floats
#define WS_Y     2402624        // bf16[2*32*64000] = 2048000 floats

#define REPACK_BLOCKS (PD*PD*BB)                  // 3528
#define NW_ELEMS  (2*2*27*64*8)                   // 55296
#define PREP_ELEMS (NW_ELEMS + 64 + NSLOT*64)     // wfrag + bias + zero sums2
#define PREP_BLOCKS ((PREP_ELEMS + 255) / 256)    // 233

static __device__ __forceinline__ short f2bf(float f) {
    __hip_bfloat16 h = __float2bfloat16(f);
    return *reinterpret_cast<short*>(&h);
}
static __device__ __forceinline__ float bf2f(short s) {
    union { unsigned u; float f; } cv;
    cv.u = ((unsigned)(unsigned short)s) << 16;
    return cv.f;
}

// ---------------------------------------------------------------------------
// Kernel 1: fused prep (routing + B-fragment weights + bias + zero stat slots)
//           and channels-last zero-padded bf16 repack of x. (r5-verified)
// ---------------------------------------------------------------------------
__global__ void prep_repack_kernel(const float* __restrict__ x,
                                   const float* __restrict__ emb,
                                   const float* __restrict__ rw,
                                   const float* __restrict__ rb,
                                   const float* __restrict__ ek,
                                   const float* __restrict__ ebias,
                                   float* __restrict__ ws) {
    __shared__ __hip_bfloat16 tile[PD * 32];   // 2688 B, layout [xp][i]
    const int bid = blockIdx.x;
    const int t = threadIdx.x;
    if (bid < REPACK_BLOCKS) {
        // ---- repack role ----
        int b  = bid / (PD * PD);
        int r  = bid % (PD * PD);
        int zp = r / PD, yp = r % PD;
        __hip_bfloat16* row = (__hip_bfloat16*)(ws + WS_XPAD2) +
                              ((((size_t)b * PD + zp) * PD + yp) * PD) * 32;
        const bool inz = (zp >= 1 && zp <= DM && yp >= 1 && yp <= DM);
        const int i  = t >> 3;          // channel 0..31
        const int xl = t & 7;           // x-lane within 8
        #pragma unroll
        for (int k = 0; k < 6; ++k) {
            int xp = xl + 8 * k;
            if (xp < PD) {
                float v = 0.0f;
                if (inz && xp >= 1 && xp <= DM)
                    v = x[(size_t)(b * CIN + i) * NVOL +
                          (zp - 1) * NPTS + (yp - 1) * DM + (xp - 1)];
                tile[xp * 32 + i] = __float2bfloat16(v);
            }
        }
        __syncthreads();
        // flat coalesced copy: 672 dwords
        const unsigned* ts = (const unsigned*)tile;
        unsigned* rowu = (unsigned*)row;
        for (int j = t; j < PD * 32 / 2; j += 256) rowu[j] = ts[j];
        return;
    }
    // ---- prep role ----
    int idx = (bid - REPACK_BLOCKS) * 256 + t;
    __hip_bfloat16* wfrag = (__hip_bfloat16*)(ws + WS_WFRAG);
    if (idx < NW_ELEMS) {
        int j    = idx & 7;
        int lane = (idx >> 3) & 63;
        int tap  = (idx >> 9) % 27;
        int nt   = (idx / (27 * 512)) & 1;
        int b    = idx / (2 * 27 * 512);
        int o = nt * 16 + (lane & 15);
        int i = (lane >> 4) * 8 + j;
        float e0 = emb[b];
        float w = 0.0f;
        #pragma unroll
        for (int e = 0; e < 3; ++e) {
            float r = 1.0f / (1.0f + expf(-(e0 * rw[e] + rb[e])));
            w += r * ek[((e * COUT + o) * CIN + i) * 27 + tap];
        }
        wfrag[idx] = __float2bfloat16(w);
    } else if (idx < NW_ELEMS + 64) {
        int j2 = idx - NW_ELEMS;
        int b = j2 >> 5, o = j2 & 31;
        float e0 = emb[b];
        float bv = 0.0f;
        #pragma unroll
        for (int e = 0; e < 3; ++e) {
            float r = 1.0f / (1.0f + expf(-(e0 * rw[e] + rb[e])));
            bv += r * ebias[e * COUT + o];
        }
        ws[WS_BCOMB + j2] = bv;
    } else if (idx < PREP_ELEMS) {
        ws[WS_SUM2 + (idx - NW_ELEMS - 64)] = 0.0f;   // zero sums2[64][64]
    }
}

// ---------------------------------------------------------------------------
// Kernel 2 (REWRITTEN): LDS-staged implicit-GEMM conv.
// Per z-slice dz: the block's A-footprint is 5 CONTIGUOUS xpad rows
// (13.4 KB) -> flat coalesced stage into LDS, then 9 taps of
// ds_read_b128 A-frags + MFMA. Global A-loads/lane: 54 -> ~12; total A
// traffic 432 MB -> 80 MB (kills the 6.75x redundancy r3 measured as
// 50 MB L2-miss FETCH with MfmaUtil 5%). r9's occupancy-null showed more
// waves don't help -- fewer load instructions should.
// LDS: atile 13440 + ytile 4608 + lstat 256 = 18.3 KB -> 8 blocks/CU.
// ---------------------------------------------------------------------------
__global__ __launch_bounds__(256, 8) void conv_mfma_kernel(
        const __hip_bfloat16* __restrict__ xp2,
        const bf16x8* __restrict__ wfrag,
        const float* __restrict__ bcomb,
        __hip_bfloat16* __restrict__ y,
        float* __restrict__ sums2) {
    // XCD-affine decode (r8): flat 2000 = 8 XCDs x 250; XCD g owns z-range
    const int g   = blockIdx.x & 7;
    const int s   = blockIdx.x >> 3;
    const int b   = s / 125;
    const int rem = s % 125;
    const int z   = g * 5 + rem / 25;
    const int mc  = rem % 25;

    const int tid = threadIdx.x, lane = tid & 63, wv = tid >> 6;
    const int mt = wv & 1, nt = wv >> 1;
    const int quad = lane >> 4, l15 = lane & 15;

    __shared__ float lstat[64];
    __shared__ short ytile[32 * 72];        // [o][s], pitch 72 (16B-aligned)
    __shared__ short atile[5 * PD * 32];    // 5 y-rows x 42 x x 32 ch (13440 B)

    if (tid < 64) lstat[tid] = 0.0f;

    const int y0  = (mc * 64) / DM;         // first y-row this block touches
    const int pa0 = mc * 64 + mt * 32 + l15;
    const int pa1 = pa0 + 16;
    const int ya0 = pa0 / DM, xa0 = pa0 % DM;
    const int ya1 = pa1 / DM, xa1 = pa1 % DM;
    // LDS element offsets of the two A-frags (row-relative to y0)
    const int af0 = ((ya0 - y0) * PD + xa0) * 32 + quad * 8;
    const int af1 = ((ya1 - y0) * PD + xa1) * 32 + quad * 8;

    const bf16x8* wbase = wfrag + ((b * 2 + nt) * 27) * 64 + lane;
    const int nrows = min(5, PD - y0);      // y0=38 tail: 4 rows suffice
    const int nchunk = nrows * (PD * 32 / 8);  // 16B chunks: 168/row

    floatx4 acc0 = {0.f, 0.f, 0.f, 0.f};
    floatx4 acc1 = {0.f, 0.f, 0.f, 0.f};

    for (int dz = 0; dz < 3; ++dz) {
        __syncthreads();   // atile quiesce (also covers lstat init on dz=0)
        // stage rows y0..y0+nrows-1 of plane z+dz: contiguous in xpad
        {
            const bf16x8* src = (const bf16x8*)(xp2 +
                ((((size_t)b * PD + (z + dz)) * PD + y0) * PD) * 32);
            bf16x8* dst = (bf16x8*)atile;
            for (int j = tid; j < nchunk; j += 256) dst[j] = src[j];
        }
        __syncthreads();
        #pragma unroll
        for (int t9 = 0; t9 < 9; ++t9) {
            const int dy = t9 / 3, dx = t9 % 3;
            const int aoff = (dy * PD + dx) * 32;
            bf16x8 av0 = *(const bf16x8*)&atile[af0 + aoff];
            bf16x8 av1 = *(const bf16x8*)&atile[af1 + aoff];
            bf16x8 bv  = wbase[(dz * 9 + t9) * 64];
            acc0 = __builtin_amdgcn_mfma_f32_16x16x32_bf16(av0, bv, acc0, 0, 0, 0);
            acc1 = __builtin_amdgcn_mfma_f32_16x16x32_bf16(av1, bv, acc1, 0, 0, 0);
        }
    }

    const int o = nt * 16 + l15;
    const float bias = bcomb[b * COUT + o];

    float u0 = acc0[0] + bias, u1 = acc0[1] + bias;
    float u2 = acc0[2] + bias, u3 = acc0[3] + bias;
    float w0 = acc1[0] + bias, w1 = acc1[1] + bias;
    float w2 = acc1[2] + bias, w3 = acc1[3] + bias;

    {
        const int s0 = mt * 32 + quad * 4;
        bf16x4 p0 = { f2bf(u0), f2bf(u1), f2bf(u2), f2bf(u3) };
        bf16x4 p1 = { f2bf(w0), f2bf(w1), f2bf(w2), f2bf(w3) };
        *(bf16x4*)&ytile[o * 72 + s0]      = p0;
        *(bf16x4*)&ytile[o * 72 + s0 + 16] = p1;
    }

    float vs = u0 + u1 + u2 + u3 + w0 + w1 + w2 + w3;
    float vq = u0*u0 + u1*u1 + u2*u2 + u3*u3 + w0*w0 + w1*w1 + w2*w2 + w3*w3;
    vs += __shfl_xor(vs, 16); vq += __shfl_xor(vq, 16);
    vs += __shfl_xor(vs, 32); vq += __shfl_xor(vq, 32);
    if (lane < 16) {
        atomicAdd(&lstat[o],      vs);
        atomicAdd(&lstat[32 + o], vq);
    }
    __syncthreads();   // covers ytile writes + lstat atomics

    {
        const int o2 = tid >> 3, c = tid & 7;
        bf16x8 v = *(const bf16x8*)&ytile[o2 * 72 + c * 8];
        __hip_bfloat16* dst = y + ((size_t)(b * COUT + o2) * DM + z) * NPTS
                            + mc * 64 + c * 8;
        *(bf16x8*)dst = v;
    }
    if (tid < 64) {
        int slot = ((b * DM + z) * 25 + mc) & (NSLOT - 1);
        atomicAdd(&sums2[slot * 64 + tid], lstat[tid]);
    }
}

// ---------------------------------------------------------------------------
// Kernel 3: plane-based BN + LeakyReLU + upsample. (r5-verified)
// ---------------------------------------------------------------------------
__global__ __launch_bounds__(256) void upsample_kernel(
        const __hip_bfloat16* __restrict__ yin,
        const float* __restrict__ sums2,
        const float* __restrict__ gamma,
        const float* __restrict__ beta,
        float* __restrict__ out) {
    __shared__ float partl[4][64];
    __shared__ float ssc[32], ssh[32];
    __shared__ float fplane[NPTS];          // normalized src plane (6.4 KB)
    const int tid = threadIdx.x;
    const int cc  = blockIdx.x / DM;        // b*COUT + c
    const int z   = blockIdx.x % DM;
    const int c   = cc & 31;

    // Phase A: reduce 64 stat slots -> per-channel scale/shift
    {
        int sg = tid >> 6, st = tid & 63;
        float p = 0.0f;
        #pragma unroll
        for (int s = 0; s < 16; ++s) p += sums2[(sg * 16 + s) * 64 + st];
        partl[sg][st] = p;
    }
    __syncthreads();
    if (tid < 64) {
        partl[0][tid] += partl[1][tid] + partl[2][tid] + partl[3][tid];
    }
    __syncthreads();
    if (tid < 32) {
        const float invN = 1.0f / (float)(BB * NVOL);
        float mean  = partl[0][tid] * invN;
        float var   = partl[0][32 + tid] * invN - mean * mean;
        float scale = gamma[tid] * rsqrtf(var + EPSBN);
        ssc[tid] = scale;
        ssh[tid] = beta[tid] - mean * scale;
    }
    __syncthreads();

    // Phase B: normalize src plane into LDS (200 threads x bf16x8 = 16B loads)
    const float sc = ssc[c], sh = ssh[c];
    if (tid < NPTS / 8) {
        bf16x8 rv = *(const bf16x8*)(yin + ((size_t)cc * DM + z) * NPTS + tid * 8);
        #pragma unroll
        for (int j = 0; j < 8; ++j) {
            float v = bf2f(rv[j]) * sc + sh;
            fplane[tid * 8 + j] = (v >= 0.0f) ? v : 0.1f * v;
        }
    }
    __syncthreads();

    // Phase C: write dst planes 2z and 2z+1 as lane-consecutive floatx4 chunks
    float* outp = out + ((size_t)cc * 80 + 2 * z) * 6400;
    #pragma unroll 2
    for (int cch = tid; cch < 2 * 1600; cch += 256) {
        int plane = cch / 1600;
        int cp    = cch - plane * 1600;
        int yy2   = cp / 20;
        int sx0   = (cp % 20) * 2;
        const float* srow = fplane + (yy2 >> 1) * DM;
        float v0 = srow[sx0], v1 = srow[sx0 + 1];
        floatx4 q = {v0, v0, v1, v1};
        *(floatx4*)(outp + (size_t)plane * 6400 + cp * 4) = q;
    }
}

// ---------------------------------------------------------------------------
extern "C" void kernel_launch(void* const* d_in, const int* in_sizes, int n_in,
                              void* d_out, int out_size, void* d_ws, size_t ws_size,
                              hipStream_t stream) {
    const float* x     = (const float*)d_in[0];
    const float* emb   = (const float*)d_in[1];
    const float* rw    = (const float*)d_in[2];
    const float* rb    = (const float*)d_in[3];
    const float* ek    = (const float*)d_in[4];
    const float* ebias = (const float*)d_in[5];
    const float* gamma = (const float*)d_in[6];
    const float* beta  = (const float*)d_in[7];
    float* ws  = (float*)d_ws;
    float* out = (float*)d_out;

    // 1: prep + repack (+ zero stat slots)
    prep_repack_kernel<<<REPACK_BLOCKS + PREP_BLOCKS, 256, 0, stream>>>(
        x, emb, rw, rb, ek, ebias, ws);

    // 2: LDS-staged MFMA conv, XCD-affine flat grid (2000 = 8 x 250)
    conv_mfma_kernel<<<2000, 256, 0, stream>>>(
        (const __hip_bfloat16*)(ws + WS_XPAD2), (const bf16x8*)(ws + WS_WFRAG),
        ws + WS_BCOMB, (__hip_bfloat16*)(ws + WS_Y), ws + WS_SUM2);

    // 3: plane-based BN + LeakyReLU + upsample
    upsample_kernel<<<BB * COUT * DM, 256, 0, stream>>>(
        (const __hip_bfloat16*)(ws + WS_Y), ws + WS_SUM2, gamma, beta, out);
}